// Round 1
// baseline (878.193 us; speedup 1.0000x reference)
//
#include <hip/hip_runtime.h>
#include <math.h>

#define BSZ 16384
#define MB  19
#define KIN 4864   // M*DIM

typedef __attribute__((ext_vector_type(8))) short short8;
typedef __attribute__((ext_vector_type(4))) float float4v;

static __device__ inline unsigned short f2bf(float f) {
  union { float f; unsigned u; } c; c.f = f;
  unsigned r = c.u + 0x7FFF + ((c.u >> 16) & 1);   // RTNE
  return (unsigned short)(r >> 16);
}

// ---------------- kw: W1 -> bf16 ----------------
__global__ __launch_bounds__(256) void kw_w1b(const float* __restrict__ W1,
                                              unsigned short* __restrict__ W1b) {
  int i = blockIdx.x * 256 + threadIdx.x;   // 128*256 = 32768
  W1b[i] = f2bf(W1[i]);
}

// ---------------- kp: fold Wf into Wg; emit bf16 Wall[m][o][384] + bc ------
__global__ __launch_bounds__(128) void kp_combine(
    const float* __restrict__ Wg, const float* __restrict__ Wf,
    const float* __restrict__ bf, const float* __restrict__ bg,
    unsigned short* __restrict__ Wall, float* __restrict__ bc) {
  int mo = blockIdx.x;        // m*256 + o
  int m = mo >> 8;
  int d = threadIdx.x;
  __shared__ float wg_s[128];
  wg_s[d] = Wg[(size_t)mo * 384 + d];
  __syncthreads();
  float acc = 0.f;
  for (int k = 0; k < 128; ++k)
    acc = fmaf(wg_s[k], Wf[(m * 128 + k) * 128 + d], acc);
  unsigned short* wr = Wall + (size_t)mo * 384;
  wr[d]       = f2bf(acc);
  wr[128 + d] = f2bf(Wg[(size_t)mo * 384 + 128 + d]);
  wr[256 + d] = f2bf(Wg[(size_t)mo * 384 + 256 + d]);
  if (d == 0) {
    float b = bg[mo];
    for (int k = 0; k < 128; ++k) b = fmaf(wg_s[k], bf[m * 128 + k], b);
    bc[mo] = b;
  }
}

// ---------------- k1: fea_u (bf16) + fc1 via MFMA + ReLU + fused stats -----
// 512 thr = 8 waves, 32 rows/block, grid 512. h_pre stored bf16 (k3 consumes
// bf16 anyway -> bit-identical, halves h_pre HBM traffic).
__global__ __launch_bounds__(512) void k1_mfma(
    const float* __restrict__ x, const unsigned short* __restrict__ W1b,
    const float* __restrict__ b1, unsigned short* __restrict__ h_pre,
    float* __restrict__ gsum, float* __restrict__ gsq) {
  __shared__ unsigned short fuB[32][272];   // pitch 272 shorts: optimal b128 reads
  __shared__ float bs[128], bq[128];
  const int t = threadIdx.x, b0 = blockIdx.x * 32;
  const int w = t >> 6, l = t & 63;

  // phase A: fea_u = sum_m x3, to bf16 LDS
#pragma unroll
  for (int i = 0; i < 4; ++i) {
    int r = w * 4 + i;
    const float* xr = x + (size_t)(b0 + r) * KIN + l * 4;
    float4 s = {0.f, 0.f, 0.f, 0.f};
    for (int m = 0; m < MB; ++m) {
      float4 v = *(const float4*)(xr + m * 256);
      s.x += v.x; s.y += v.y; s.z += v.z; s.w += v.w;
    }
    ushort4 u;
    u.x = f2bf(s.x); u.y = f2bf(s.y); u.z = f2bf(s.z); u.w = f2bf(s.w);
    *(ushort4*)&fuB[r][l * 4] = u;
  }
  if (t < 128) { bs[t] = 0.f; bq[t] = 0.f; }
  __syncthreads();

  // phase B: h = relu(fea_u @ W1^T + b1), MFMA; wave w -> d in [16w, 16w+16)
  const int col = l & 15, q = l >> 4;
  const int d = w * 16 + col;
  float bv = b1[d];
  float4v acc0 = {bv, bv, bv, bv}, acc1 = {bv, bv, bv, bv};
#pragma unroll
  for (int ks = 0; ks < 8; ++ks) {
    short8 a0 = *(const short8*)&fuB[col][ks * 32 + q * 8];
    short8 a1 = *(const short8*)&fuB[16 + col][ks * 32 + q * 8];
    short8 b  = *(const short8*)(W1b + d * 256 + ks * 32 + q * 8);
    acc0 = __builtin_amdgcn_mfma_f32_16x16x32_bf16(a0, b, acc0, 0, 0, 0);
    acc1 = __builtin_amdgcn_mfma_f32_16x16x32_bf16(a1, b, acc1, 0, 0, 0);
  }
  float s = 0.f, qq = 0.f;
#pragma unroll
  for (int j = 0; j < 4; ++j) {
    float v0 = fmaxf(acc0[j], 0.f);
    float v1 = fmaxf(acc1[j], 0.f);
    h_pre[(size_t)(b0 + q * 4 + j) * 128 + d]      = f2bf(v0);
    h_pre[(size_t)(b0 + 16 + q * 4 + j) * 128 + d] = f2bf(v1);
    s += v0 + v1; qq = fmaf(v0, v0, qq); qq = fmaf(v1, v1, qq);
  }
  atomicAdd(&bs[d], s);
  atomicAdd(&bq[d], qq);
  __syncthreads();
  if (t < 128) { atomicAdd(&gsum[t], bs[t]); atomicAdd(&gsq[t], bq[t]); }
}

// ---------------- k2b: BN -> fold into W2 (bf16 W2s, f32 b2s) --------------
__global__ __launch_bounds__(128) void k2b_finalize(
    const float* __restrict__ gsum, const float* __restrict__ gsq,
    const float* __restrict__ gamma, const float* __restrict__ beta,
    const float* __restrict__ W2, const float* __restrict__ b2,
    unsigned short* __restrict__ W2s, float* __restrict__ b2s) {
  __shared__ float sc[128], sh[128];
  int d = threadIdx.x;
  float mu  = gsum[d] * (1.f / BSZ);
  float var = gsq[d]  * (1.f / BSZ) - mu * mu;
  float s   = gamma[d] * rsqrtf(var + 1e-5f);
  sc[d] = s;
  sh[d] = beta[d] - mu * s;
  __syncthreads();
  float acc = b2[d];
  for (int k = 0; k < 128; ++k) {
    float w2 = W2[d * 128 + k];
    W2s[d * 128 + k] = f2bf(w2 * sc[k]);
    acc = fmaf(w2, sh[k], acc);
  }
  b2s[d] = acc;
}

// ---------------- k3: fc2-MFMA + logits-MFMA + softmax-mix, fused ----------
// 512 thr = 8 waves, 32 rows/block, grid 512. Double-buffered g staging,
// att transposed through LDS for coalesced x mixing. 2 blocks/CU target.
__global__ __launch_bounds__(512, 4) void k3_fused(
    const float* __restrict__ x, const float* __restrict__ g,
    const unsigned short* __restrict__ h_pre,
    const unsigned short* __restrict__ W2s, const float* __restrict__ b2s,
    const unsigned short* __restrict__ Wall, const float* __restrict__ bc,
    float* __restrict__ out) {
  __shared__ unsigned short fz[32][144];        // 9.2 KB  (pitch 144: optimal b128)
  __shared__ unsigned short gb[2][32][272];     // 34.8 KB (pitch 272: optimal b128)
  __shared__ float att[32][260];                // 33.3 KB (pitch 260: optimal b128)
  const int t = threadIdx.x, b0 = blockIdx.x * 32;
  const int w = t >> 6, l = t & 63;
  const int col = l & 15, q = l >> 4;

  // ---- phase 0a: fc2 via MFMA; wave w -> d in [16w, 16w+16) ----
  {
    const int d = w * 16 + col;
    float bv = b2s[d];
    float4v a2_0 = {bv, bv, bv, bv}, a2_1 = {bv, bv, bv, bv};
#pragma unroll
    for (int ks = 0; ks < 4; ++ks) {
      short8 A0 = *(const short8*)(h_pre + (size_t)(b0 + col) * 128 + ks * 32 + q * 8);
      short8 A1 = *(const short8*)(h_pre + (size_t)(b0 + 16 + col) * 128 + ks * 32 + q * 8);
      short8 B  = *(const short8*)(W2s + d * 128 + ks * 32 + q * 8);
      a2_0 = __builtin_amdgcn_mfma_f32_16x16x32_bf16(A0, B, a2_0, 0, 0, 0);
      a2_1 = __builtin_amdgcn_mfma_f32_16x16x32_bf16(A1, B, a2_1, 0, 0, 0);
    }
#pragma unroll
    for (int j = 0; j < 4; ++j) {
      fz[q * 4 + j][d]      = f2bf(a2_0[j]);
      fz[16 + q * 4 + j][d] = f2bf(a2_1[j]);
    }
  }
  // ---- phase 0b: stage g(m=0) -> gb[0] ----
#pragma unroll
  for (int i = 0; i < 4; ++i) {
    int r = i * 8 + w;
    float4 gv = *(const float4*)(g + (size_t)(b0 + r) * KIN + l * 4);
    ushort4 u;
    u.x = f2bf(gv.x); u.y = f2bf(gv.y); u.z = f2bf(gv.z); u.w = f2bf(gv.w);
    *(ushort4*)&gb[0][r][l * 4] = u;
  }
  __syncthreads();

  float4v Ov[4], Sm[4];
#pragma unroll
  for (int u = 0; u < 4; ++u) { Ov[u] = float4v{0,0,0,0}; Sm[u] = float4v{0,0,0,0}; }

  const int o0 = w * 32;
  const int mr = t >> 4, mc = t & 15;   // mix-phase ownership: row mr, cols 4*mc + 64u

  for (int m = 0; m < MB; ++m) {
    const int p = m & 1;
    // ---- logits MFMA: wave tile 32 rows x 32 cols ----
    float bc0 = bc[m * 256 + o0 + col];
    float bc1 = bc[m * 256 + o0 + 16 + col];
    float4v acc[4];
    acc[0] = float4v{bc0, bc0, bc0, bc0};
    acc[1] = float4v{bc1, bc1, bc1, bc1};
    acc[2] = float4v{bc0, bc0, bc0, bc0};
    acc[3] = float4v{bc1, bc1, bc1, bc1};
    const unsigned short* wb0 = Wall + (size_t)(m * 256 + o0 + col) * 384;
    const unsigned short* wb1 = wb0 + (size_t)16 * 384;
#pragma unroll
    for (int ks = 0; ks < 12; ++ks) {
      short8 a0, a1;
      if (ks < 4) {
        a0 = *(const short8*)&fz[col][ks * 32 + q * 8];
        a1 = *(const short8*)&fz[16 + col][ks * 32 + q * 8];
      } else {
        a0 = *(const short8*)&gb[p][col][(ks - 4) * 32 + q * 8];
        a1 = *(const short8*)&gb[p][16 + col][(ks - 4) * 32 + q * 8];
      }
      short8 b0v = *(const short8*)(wb0 + ks * 32 + q * 8);
      short8 b1v = *(const short8*)(wb1 + ks * 32 + q * 8);
      acc[0] = __builtin_amdgcn_mfma_f32_16x16x32_bf16(a0, b0v, acc[0], 0, 0, 0);
      acc[1] = __builtin_amdgcn_mfma_f32_16x16x32_bf16(a0, b1v, acc[1], 0, 0, 0);
      acc[2] = __builtin_amdgcn_mfma_f32_16x16x32_bf16(a1, b0v, acc[2], 0, 0, 0);
      acc[3] = __builtin_amdgcn_mfma_f32_16x16x32_bf16(a1, b1v, acc[3], 0, 0, 0);
    }
    // exp -> att_s (transpose through LDS; writes are 2-way = free)
#pragma unroll
    for (int rt = 0; rt < 2; ++rt) {
#pragma unroll
      for (int j = 0; j < 4; ++j) {
        int row = rt * 16 + q * 4 + j;
        att[row][o0 + col]      = __expf(acc[rt * 2 + 0][j]);
        att[row][o0 + 16 + col] = __expf(acc[rt * 2 + 1][j]);
      }
    }
    __syncthreads();

    // ---- mix phase: coalesced x + att from LDS; plus stage g(m+1) ----
    {
      const float* xr = x + (size_t)(b0 + mr) * KIN + m * 256 + mc * 4;
#pragma unroll
      for (int u = 0; u < 4; ++u) {
        float4 xv = *(const float4*)(xr + u * 64);
        float4 ev = *(const float4*)&att[mr][mc * 4 + u * 64];
        Sm[u][0] += ev.x; Sm[u][1] += ev.y; Sm[u][2] += ev.z; Sm[u][3] += ev.w;
        Ov[u][0] = fmaf(ev.x, xv.x, Ov[u][0]);
        Ov[u][1] = fmaf(ev.y, xv.y, Ov[u][1]);
        Ov[u][2] = fmaf(ev.z, xv.z, Ov[u][2]);
        Ov[u][3] = fmaf(ev.w, xv.w, Ov[u][3]);
      }
    }
    if (m + 1 < MB) {
#pragma unroll
      for (int i = 0; i < 4; ++i) {
        int r = i * 8 + w;
        float4 gv = *(const float4*)(g + (size_t)(b0 + r) * KIN + (m + 1) * 256 + l * 4);
        ushort4 u;
        u.x = f2bf(gv.x); u.y = f2bf(gv.y); u.z = f2bf(gv.z); u.w = f2bf(gv.w);
        *(ushort4*)&gb[1 - p][r][l * 4] = u;
      }
    }
    __syncthreads();
  }

  // ---- epilogue ----
#pragma unroll
  for (int u = 0; u < 4; ++u) {
    float4 o4;
    o4.x = Ov[u][0] / Sm[u][0];
    o4.y = Ov[u][1] / Sm[u][1];
    o4.z = Ov[u][2] / Sm[u][2];
    o4.w = Ov[u][3] / Sm[u][3];
    *(float4*)(out + (size_t)(b0 + mr) * 256 + mc * 4 + u * 64) = o4;
  }
}

extern "C" void kernel_launch(void* const* d_in, const int* in_sizes, int n_in,
                              void* d_out, int out_size, void* d_ws, size_t ws_size,
                              hipStream_t stream) {
  const float* x     = (const float*)d_in[0];
  const float* g     = (const float*)d_in[1];
  const float* W1    = (const float*)d_in[2];
  const float* b1    = (const float*)d_in[3];
  const float* gamma = (const float*)d_in[4];
  const float* beta  = (const float*)d_in[5];
  const float* W2    = (const float*)d_in[6];
  const float* b2    = (const float*)d_in[7];
  const float* Wf    = (const float*)d_in[8];
  const float* bf    = (const float*)d_in[9];
  const float* Wg    = (const float*)d_in[10];
  const float* bg    = (const float*)d_in[11];
  float* out = (float*)d_out;

  float* ws = (float*)d_ws;
  float* gsum = ws;                                   // 128
  float* gsq  = gsum + 128;                           // 128
  float* bc   = gsq + 128;                            // 19*256 = 4864
  float* b2s  = bc + MB * 256;                        // 128
  unsigned short* Wall = (unsigned short*)(b2s + 128);            // 19*256*384
  unsigned short* W1b  = Wall + (size_t)MB * 256 * 384;           // 128*256
  unsigned short* W2s  = W1b + 128 * 256;                         // 128*128
  unsigned short* h_pre = W2s + 128 * 128;                        // 16384*128 (bf16)

  hipMemsetAsync(gsum, 0, 256 * sizeof(float), stream);
  kw_w1b<<<128, 256, 0, stream>>>(W1, W1b);
  kp_combine<<<MB * 256, 128, 0, stream>>>(Wg, Wf, bf, bg, Wall, bc);
  k1_mfma<<<BSZ / 32, 512, 0, stream>>>(x, W1b, b1, h_pre, gsum, gsq);
  k2b_finalize<<<1, 128, 0, stream>>>(gsum, gsq, gamma, beta, W2, b2, W2s, b2s);
  k3_fused<<<BSZ / 32, 512, 0, stream>>>(x, g, h_pre, W2s, b2s, Wall, bc, out);
}